// Round 1
// baseline (1506.263 us; speedup 1.0000x reference)
//
#include <hip/hip_runtime.h>

#define NN 50000
#define NE 1200000
#define CCH 64
#define NLAYER 8
#define HID 128
#define NG 128
#define BN_EPS 1e-5f

// ---- workspace layout (offsets in floats) ----
// [stats(9*128) | pooled(128*64) | counts(128)]  <- zeroed by one memsetAsync
// deg(N) dis(N) offs(N+1 pad) cursor(N) csr_src(E) csr_nrm(E) h(N*64) hw(N*64) Wp(4096) bias2(64)
enum : size_t {
  OFF_STATS  = 0,
  OFF_POOLED = 1152,
  OFF_COUNTS = 9344,
  MEMSET_F   = 9472,
  OFF_DEG    = 9472,
  OFF_DIS    = 59472,
  OFF_OFFS   = 109472,
  OFF_CURSOR = 159476,
  OFF_CSRSRC = 209476,
  OFF_CSRNRM = 1409476,
  OFF_H      = 2609476,
  OFF_HW     = 5809476,
  OFF_WP     = 9009476,
  OFF_BIAS2  = 9013572,
  WS_FLOATS  = 9013636
};

__global__ void init_deg_kernel(float* __restrict__ deg) {
  int i = blockIdx.x * blockDim.x + threadIdx.x;
  if (i < NN) deg[i] = 1.0f;  // self-loop
}

__global__ void count_deg_kernel(const int* __restrict__ ei, float* __restrict__ deg) {
  int e = blockIdx.x * blockDim.x + threadIdx.x;
  if (e < NE) atomicAdd(&deg[ei[NE + e]], 1.0f);
}

__global__ void dis_kernel(const float* __restrict__ deg, float* __restrict__ dis) {
  int i = blockIdx.x * blockDim.x + threadIdx.x;
  if (i < NN) dis[i] = rsqrtf(deg[i]);
}

__global__ __launch_bounds__(1024) void scan_kernel(const float* __restrict__ deg,
    int* __restrict__ offs, int* __restrict__ cursor) {
  __shared__ int part[1024];
  int t = threadIdx.x;
  const int CHK = (NN + 1023) / 1024;  // 49
  int base = t * CHK;
  int hi = base + CHK; if (hi > NN) hi = NN;
  int s = 0;
  for (int i = base; i < hi; ++i) s += (int)deg[i] - 1;  // in-degree w/o self-loop
  part[t] = s;
  __syncthreads();
  for (int d = 1; d < 1024; d <<= 1) {
    int v = (t >= d) ? part[t - d] : 0;
    __syncthreads();
    if (t >= d) part[t] += v;
    __syncthreads();
  }
  int prefix = (t == 0) ? 0 : part[t - 1];
  for (int i = base; i < hi; ++i) {
    offs[i] = prefix; cursor[i] = prefix;
    prefix += (int)deg[i] - 1;
  }
  if (t == 1023) offs[NN] = prefix;
}

__global__ void csr_fill_kernel(const int* __restrict__ ei, const float* __restrict__ dis,
    int* __restrict__ cursor, int* __restrict__ csr_src, float* __restrict__ csr_nrm) {
  int e = blockIdx.x * blockDim.x + threadIdx.x;
  if (e < NE) {
    int r = ei[e], c = ei[NE + e];
    int p = atomicAdd(&cursor[c], 1);
    csr_src[p] = r;
    csr_nrm[p] = dis[r] * dis[c];
  }
}

// h = emb[x]; also accumulate BN stats for layer 0
__global__ __launch_bounds__(256) void embed_stats_kernel(const int* __restrict__ x,
    const float* __restrict__ emb, float* __restrict__ h, float* __restrict__ stats0) {
  int c = threadIdx.x & 63;
  int wave = (blockIdx.x * blockDim.x + threadIdx.x) >> 6;
  int nw = (gridDim.x * blockDim.x) >> 6;
  float ls = 0.f, lq = 0.f;
  for (int i = wave; i < NN; i += nw) {
    float v = emb[x[i] * CCH + c];
    h[(size_t)i * CCH + c] = v;
    ls += v; lq += v * v;
  }
  __shared__ float s1[256], s2[256];
  s1[threadIdx.x] = ls; s2[threadIdx.x] = lq;
  __syncthreads();
  if (threadIdx.x < 64) {
    float a = s1[threadIdx.x] + s1[threadIdx.x + 64] + s1[threadIdx.x + 128] + s1[threadIdx.x + 192];
    float b = s2[threadIdx.x] + s2[threadIdx.x + 64] + s2[threadIdx.x + 128] + s2[threadIdx.x + 192];
    atomicAdd(&stats0[c], a);
    atomicAdd(&stats0[64 + c], b);
  }
}

// Fold BN into GEMM: Wp[k][j] = a[k]*W[k][j], bias2[j] = sum_k b2[k]*W[k][j]
__global__ __launch_bounds__(256) void bn_make_kernel(const float* __restrict__ stats,
    const float* __restrict__ gamma, const float* __restrict__ beta,
    const float* __restrict__ W, float* __restrict__ Wp, float* __restrict__ bias2) {
  __shared__ float a[64], b2[64];
  int t = threadIdx.x;
  if (t < 64) {
    float inv_n = 1.0f / (float)NN;
    float m = stats[t] * inv_n;
    float var = stats[64 + t] * inv_n - m * m;
    float rstd = rsqrtf(var + BN_EPS);
    float av = gamma[t] * rstd;
    a[t] = av;
    b2[t] = beta[t] - m * av;
  }
  __syncthreads();
  for (int idx = t; idx < 4096; idx += 256) {
    int k = idx >> 6;
    Wp[idx] = a[k] * W[idx];
  }
  if (t < 64) {
    float s = 0.f;
    for (int k = 0; k < 64; ++k) s += b2[k] * W[k * 64 + t];
    bias2[t] = s;
  }
}

// hw = h @ Wp + bias2 ; 128-node tile, 8x4 register tile per thread
__global__ __launch_bounds__(256) void gemm_kernel(const float* __restrict__ h,
    const float* __restrict__ Wp, const float* __restrict__ bias2, float* __restrict__ hw) {
  __shared__ float Ws[64 * 64];
  __shared__ float HsT[64 * 132];  // [k][node], stride 132: conflict-free b128 reads
  int tid = threadIdx.x;
  int nodeBase = blockIdx.x * 128;
  for (int idx = tid; idx < 4096; idx += 256) Ws[idx] = Wp[idx];
  for (int idx = tid; idx < 8192; idx += 256) {
    int node = idx >> 6, c = idx & 63;
    int gn = nodeBase + node;
    float v = (gn < NN) ? h[(size_t)gn * CCH + c] : 0.f;
    HsT[c * 132 + node] = v;
  }
  __syncthreads();
  int tc = tid & 15;   // channels tc*4..+3
  int tr = tid >> 4;   // nodes tr*8..+7
  float4 bb = *(const float4*)&bias2[tc * 4];
  float acc[8][4];
#pragma unroll
  for (int i = 0; i < 8; ++i) { acc[i][0] = bb.x; acc[i][1] = bb.y; acc[i][2] = bb.z; acc[i][3] = bb.w; }
#pragma unroll 2
  for (int k = 0; k < 64; ++k) {
    float4 wv = *(const float4*)&Ws[k * 64 + tc * 4];
    float4 h0 = *(const float4*)&HsT[k * 132 + tr * 8];
    float4 h1 = *(const float4*)&HsT[k * 132 + tr * 8 + 4];
    float hv[8] = {h0.x, h0.y, h0.z, h0.w, h1.x, h1.y, h1.z, h1.w};
    float wl[4] = {wv.x, wv.y, wv.z, wv.w};
#pragma unroll
    for (int i = 0; i < 8; ++i)
#pragma unroll
      for (int j = 0; j < 4; ++j) acc[i][j] = fmaf(hv[i], wl[j], acc[i][j]);
  }
#pragma unroll
  for (int i = 0; i < 8; ++i) {
    int gn = nodeBase + tr * 8 + i;
    if (gn < NN) {
      float4 o; o.x = acc[i][0]; o.y = acc[i][1]; o.z = acc[i][2]; o.w = acc[i][3];
      *(float4*)&hw[(size_t)gn * CCH + tc * 4] = o;
    }
  }
}

// h = relu(h + conv_b + self + sum_in_edges hw[src]*nrm); fused BN stats for next layer
__global__ __launch_bounds__(256) void aggregate_kernel(float* __restrict__ h,
    const float* __restrict__ hw, const float* __restrict__ dis,
    const int* __restrict__ offs, const int* __restrict__ csr_src,
    const float* __restrict__ csr_nrm, const float* __restrict__ conv_b_l,
    float* __restrict__ stats_next) {
  int c = threadIdx.x & 63;
  int wave = (blockIdx.x * blockDim.x + threadIdx.x) >> 6;
  int nw = (gridDim.x * blockDim.x) >> 6;
  float cb = conv_b_l[c];
  float ls = 0.f, lq = 0.f;
  for (int i = wave; i < NN; i += nw) {
    float d = dis[i];
    float acc = cb + hw[(size_t)i * CCH + c] * (d * d);
    int e0 = offs[i], e1 = offs[i + 1];
    int e = e0;
    for (; e + 4 <= e1; e += 4) {
      int s0 = csr_src[e], s1i = csr_src[e + 1], s2i = csr_src[e + 2], s3i = csr_src[e + 3];
      float n0 = csr_nrm[e], n1 = csr_nrm[e + 1], n2 = csr_nrm[e + 2], n3 = csr_nrm[e + 3];
      float v0 = hw[(size_t)s0 * CCH + c];
      float v1 = hw[(size_t)s1i * CCH + c];
      float v2 = hw[(size_t)s2i * CCH + c];
      float v3 = hw[(size_t)s3i * CCH + c];
      acc = fmaf(v0, n0, acc); acc = fmaf(v1, n1, acc);
      acc = fmaf(v2, n2, acc); acc = fmaf(v3, n3, acc);
    }
    for (; e < e1; ++e) {
      int s = csr_src[e];
      acc = fmaf(hw[(size_t)s * CCH + c], csr_nrm[e], acc);
    }
    float v = h[(size_t)i * CCH + c] + acc;
    v = v > 0.f ? v : 0.f;
    h[(size_t)i * CCH + c] = v;
    ls += v; lq += v * v;
  }
  __shared__ float s1[256], s2[256];
  s1[threadIdx.x] = ls; s2[threadIdx.x] = lq;
  __syncthreads();
  if (threadIdx.x < 64) {
    float a = s1[threadIdx.x] + s1[threadIdx.x + 64] + s1[threadIdx.x + 128] + s1[threadIdx.x + 192];
    float b = s2[threadIdx.x] + s2[threadIdx.x + 64] + s2[threadIdx.x + 128] + s2[threadIdx.x + 192];
    atomicAdd(&stats_next[c], a);
    atomicAdd(&stats_next[64 + c], b);
  }
}

__global__ __launch_bounds__(256) void pool_kernel(const float* __restrict__ h,
    const int* __restrict__ batch, float* __restrict__ pooled, float* __restrict__ counts) {
  int c = threadIdx.x & 63;
  int wave = (blockIdx.x * blockDim.x + threadIdx.x) >> 6;
  int nw = (gridDim.x * blockDim.x) >> 6;
  for (int i = wave; i < NN; i += nw) {
    int g = batch[i];
    atomicAdd(&pooled[g * CCH + c], h[(size_t)i * CCH + c]);
    if (c == 0) atomicAdd(&counts[g], 1.0f);
  }
}

__global__ __launch_bounds__(128) void mlp_kernel(const float* __restrict__ pooled,
    const float* __restrict__ counts, const float* __restrict__ hid_w,
    const float* __restrict__ hid_b, const float* __restrict__ out_w,
    const float* __restrict__ out_b, float* __restrict__ out) {
  int g = blockIdx.x;
  int t = threadIdx.x;  // 128 threads
  __shared__ float p[64], hid[128];
  if (t < 64) {
    float cnt = counts[g];
    cnt = cnt > 1.f ? cnt : 1.f;
    p[t] = pooled[g * CCH + t] / cnt;
  }
  __syncthreads();
  float acc = hid_b[t];
  for (int k = 0; k < 64; ++k) acc = fmaf(p[k], hid_w[k * HID + t], acc);
  acc = acc > 0.f ? acc : 0.f;
  hid[t] = acc;
  __syncthreads();
  if (t < 64) {
    float o = out_b[t];
    for (int j = 0; j < 128; ++j) o = fmaf(hid[j], out_w[j * CCH + t], o);
    out[g * CCH + t] = o;
  }
}

extern "C" void kernel_launch(void* const* d_in, const int* in_sizes, int n_in,
                              void* d_out, int out_size, void* d_ws, size_t ws_size,
                              hipStream_t stream) {
  const int* x       = (const int*)d_in[0];
  const int* ei      = (const int*)d_in[1];
  const int* batch   = (const int*)d_in[2];
  const float* emb   = (const float*)d_in[3];
  const float* gamma = (const float*)d_in[4];
  const float* beta  = (const float*)d_in[5];
  const float* convw = (const float*)d_in[6];
  const float* convb = (const float*)d_in[7];
  const float* hid_w = (const float*)d_in[8];
  const float* hid_b = (const float*)d_in[9];
  const float* out_w = (const float*)d_in[10];
  const float* out_b = (const float*)d_in[11];
  float* out = (float*)d_out;

  float* ws     = (float*)d_ws;
  float* stats  = ws + OFF_STATS;
  float* pooled = ws + OFF_POOLED;
  float* counts = ws + OFF_COUNTS;
  float* deg    = ws + OFF_DEG;
  float* dis    = ws + OFF_DIS;
  int*   offs   = (int*)(ws + OFF_OFFS);
  int*   cursor = (int*)(ws + OFF_CURSOR);
  int*   csrsrc = (int*)(ws + OFF_CSRSRC);
  float* csrnrm = ws + OFF_CSRNRM;
  float* h      = ws + OFF_H;
  float* hw     = ws + OFF_HW;
  float* wp     = ws + OFF_WP;
  float* bias2  = ws + OFF_BIAS2;

  hipMemsetAsync(ws, 0, MEMSET_F * sizeof(float), stream);
  init_deg_kernel<<<(NN + 255) / 256, 256, 0, stream>>>(deg);
  count_deg_kernel<<<(NE + 255) / 256, 256, 0, stream>>>(ei, deg);
  dis_kernel<<<(NN + 255) / 256, 256, 0, stream>>>(deg, dis);
  scan_kernel<<<1, 1024, 0, stream>>>(deg, offs, cursor);
  csr_fill_kernel<<<(NE + 255) / 256, 256, 0, stream>>>(ei, dis, cursor, csrsrc, csrnrm);
  embed_stats_kernel<<<512, 256, 0, stream>>>(x, emb, h, stats);

  for (int l = 0; l < NLAYER; ++l) {
    bn_make_kernel<<<1, 256, 0, stream>>>(stats + l * 128, gamma + l * 64, beta + l * 64,
                                          convw + l * 4096, wp, bias2);
    gemm_kernel<<<(NN + 127) / 128, 256, 0, stream>>>(h, wp, bias2, hw);
    aggregate_kernel<<<1024, 256, 0, stream>>>(h, hw, dis, offs, csrsrc, csrnrm,
                                               convb + l * 64, stats + (l + 1) * 128);
  }

  pool_kernel<<<512, 256, 0, stream>>>(h, batch, pooled, counts);
  mlp_kernel<<<NG, 128, 0, stream>>>(pooled, counts, hid_w, hid_b, out_w, out_b, out);
}

// Round 2
// 1257.835 us; speedup vs baseline: 1.1975x; 1.1975x over previous
//
#include <hip/hip_runtime.h>

#define NN 50000
#define NE 1200000
#define CCH 64
#define NLAYER 8
#define HID 128
#define NG 128
#define BN_EPS 1e-5f

// ---- workspace layout (offsets in floats) ----
// [stats(9*128) | pooled(128*64) | counts(128)]  <- zeroed by one memsetAsync
enum : size_t {
  OFF_STATS  = 0,
  OFF_POOLED = 1152,
  OFF_COUNTS = 9344,
  MEMSET_F   = 9472,
  OFF_DEG    = 9472,
  OFF_DIS    = 59472,
  OFF_OFFS   = 109472,
  OFF_CURSOR = 159476,
  OFF_CSRSRC = 209476,
  OFF_CSRNRM = 1409476,
  OFF_H      = 2609476,
  OFF_HW     = 5809476,
  OFF_WP     = 9009476,
  OFF_BIAS2  = 9013572,
  WS_FLOATS  = 9013636
};

__global__ void init_deg_kernel(float* __restrict__ deg) {
  int i = blockIdx.x * blockDim.x + threadIdx.x;
  if (i < NN) deg[i] = 1.0f;  // self-loop
}

__global__ void count_deg_kernel(const int* __restrict__ ei, float* __restrict__ deg) {
  int e = blockIdx.x * blockDim.x + threadIdx.x;
  if (e < NE) atomicAdd(&deg[ei[NE + e]], 1.0f);
}

__global__ void dis_kernel(const float* __restrict__ deg, float* __restrict__ dis) {
  int i = blockIdx.x * blockDim.x + threadIdx.x;
  if (i < NN) dis[i] = rsqrtf(deg[i]);
}

__global__ __launch_bounds__(1024) void scan_kernel(const float* __restrict__ deg,
    int* __restrict__ offs, int* __restrict__ cursor) {
  __shared__ int part[1024];
  int t = threadIdx.x;
  const int CHK = (NN + 1023) / 1024;  // 49
  int base = t * CHK;
  int hi = base + CHK; if (hi > NN) hi = NN;
  int s = 0;
  for (int i = base; i < hi; ++i) s += (int)deg[i] - 1;  // in-degree w/o self-loop
  part[t] = s;
  __syncthreads();
  for (int d = 1; d < 1024; d <<= 1) {
    int v = (t >= d) ? part[t - d] : 0;
    __syncthreads();
    if (t >= d) part[t] += v;
    __syncthreads();
  }
  int prefix = (t == 0) ? 0 : part[t - 1];
  for (int i = base; i < hi; ++i) {
    offs[i] = prefix; cursor[i] = prefix;
    prefix += (int)deg[i] - 1;
  }
  if (t == 1023) offs[NN] = prefix;
}

__global__ void csr_fill_kernel(const int* __restrict__ ei, const float* __restrict__ dis,
    int* __restrict__ cursor, int* __restrict__ csr_src, float* __restrict__ csr_nrm) {
  int e = blockIdx.x * blockDim.x + threadIdx.x;
  if (e < NE) {
    int r = ei[e], c = ei[NE + e];
    int p = atomicAdd(&cursor[c], 1);
    csr_src[p] = r;
    csr_nrm[p] = dis[r] * dis[c];
  }
}

// h = emb[x]; also accumulate BN stats for layer 0
__global__ __launch_bounds__(256) void embed_stats_kernel(const int* __restrict__ x,
    const float* __restrict__ emb, float* __restrict__ h, float* __restrict__ stats0) {
  int c = threadIdx.x & 63;
  int wave = (blockIdx.x * blockDim.x + threadIdx.x) >> 6;
  int nw = (gridDim.x * blockDim.x) >> 6;
  float ls = 0.f, lq = 0.f;
  for (int i = wave; i < NN; i += nw) {
    float v = emb[x[i] * CCH + c];
    h[(size_t)i * CCH + c] = v;
    ls += v; lq += v * v;
  }
  __shared__ float s1[256], s2[256];
  s1[threadIdx.x] = ls; s2[threadIdx.x] = lq;
  __syncthreads();
  if (threadIdx.x < 64) {
    float a = s1[threadIdx.x] + s1[threadIdx.x + 64] + s1[threadIdx.x + 128] + s1[threadIdx.x + 192];
    float b = s2[threadIdx.x] + s2[threadIdx.x + 64] + s2[threadIdx.x + 128] + s2[threadIdx.x + 192];
    atomicAdd(&stats0[c], a);
    atomicAdd(&stats0[64 + c], b);
  }
}

// Fold BN into GEMM: Wp[k][j] = a[k]*W[k][j], bias2[j] = sum_k b2[k]*W[k][j]
__global__ __launch_bounds__(256) void bn_make_kernel(const float* __restrict__ stats,
    const float* __restrict__ gamma, const float* __restrict__ beta,
    const float* __restrict__ W, float* __restrict__ Wp, float* __restrict__ bias2) {
  __shared__ float a[64], b2[64];
  int t = threadIdx.x;
  if (t < 64) {
    float inv_n = 1.0f / (float)NN;
    float m = stats[t] * inv_n;
    float var = stats[64 + t] * inv_n - m * m;
    float rstd = rsqrtf(var + BN_EPS);
    float av = gamma[t] * rstd;
    a[t] = av;
    b2[t] = beta[t] - m * av;
  }
  __syncthreads();
  for (int idx = t; idx < 4096; idx += 256) {
    int k = idx >> 6;
    Wp[idx] = a[k] * W[idx];
  }
  if (t < 64) {
    float s = 0.f;
    for (int k = 0; k < 64; ++k) s += b2[k] * W[k * 64 + t];
    bias2[t] = s;
  }
}

// hw = h @ Wp + bias2 ; 128-node tile, 8x4 register tile per thread
__global__ __launch_bounds__(256) void gemm_kernel(const float* __restrict__ h,
    const float* __restrict__ Wp, const float* __restrict__ bias2, float* __restrict__ hw) {
  __shared__ float Ws[64 * 64];
  __shared__ float HsT[64 * 132];  // [k][node], stride 132: conflict-free b128 reads
  int tid = threadIdx.x;
  int nodeBase = blockIdx.x * 128;
  for (int idx = tid; idx < 4096; idx += 256) Ws[idx] = Wp[idx];
  for (int idx = tid; idx < 8192; idx += 256) {
    int node = idx >> 6, c = idx & 63;
    int gn = nodeBase + node;
    float v = (gn < NN) ? h[(size_t)gn * CCH + c] : 0.f;
    HsT[c * 132 + node] = v;
  }
  __syncthreads();
  int tc = tid & 15;   // channels tc*4..+3
  int tr = tid >> 4;   // nodes tr*8..+7
  float4 bb = *(const float4*)&bias2[tc * 4];
  float acc[8][4];
#pragma unroll
  for (int i = 0; i < 8; ++i) { acc[i][0] = bb.x; acc[i][1] = bb.y; acc[i][2] = bb.z; acc[i][3] = bb.w; }
#pragma unroll 2
  for (int k = 0; k < 64; ++k) {
    float4 wv = *(const float4*)&Ws[k * 64 + tc * 4];
    float4 h0 = *(const float4*)&HsT[k * 132 + tr * 8];
    float4 h1 = *(const float4*)&HsT[k * 132 + tr * 8 + 4];
    float hv[8] = {h0.x, h0.y, h0.z, h0.w, h1.x, h1.y, h1.z, h1.w};
    float wl[4] = {wv.x, wv.y, wv.z, wv.w};
#pragma unroll
    for (int i = 0; i < 8; ++i)
#pragma unroll
      for (int j = 0; j < 4; ++j) acc[i][j] = fmaf(hv[i], wl[j], acc[i][j]);
  }
#pragma unroll
  for (int i = 0; i < 8; ++i) {
    int gn = nodeBase + tr * 8 + i;
    if (gn < NN) {
      float4 o; o.x = acc[i][0]; o.y = acc[i][1]; o.z = acc[i][2]; o.w = acc[i][3];
      *(float4*)&hw[(size_t)gn * CCH + tc * 4] = o;
    }
  }
}

// h = relu(h + conv_b + self + sum_in_edges hw[src]*nrm); fused BN stats for next layer
// Chunked node ranges per wave (sequential CSR reads), 8 independent gathers in flight.
__global__ __launch_bounds__(256) void aggregate_kernel(float* __restrict__ h,
    const float* __restrict__ hw, const float* __restrict__ dis,
    const int* __restrict__ offs, const int* __restrict__ csr_src,
    const float* __restrict__ csr_nrm, const float* __restrict__ conv_b_l,
    float* __restrict__ stats_next) {
  int c = threadIdx.x & 63;
  int wid = (blockIdx.x * blockDim.x + threadIdx.x) >> 6;
  int nw = (gridDim.x * blockDim.x) >> 6;
  int chunk = (NN + nw - 1) / nw;
  int lo = wid * chunk;
  int hi = lo + chunk; if (hi > NN) hi = NN;
  float cb = conv_b_l[c];
  float ls = 0.f, lq = 0.f;
  for (int i = lo; i < hi; ++i) {
    float d = dis[i];
    float acc = cb + hw[(size_t)i * CCH + c] * (d * d);
    int e0 = offs[i], e1 = offs[i + 1];
    int e = e0;
    for (; e + 8 <= e1; e += 8) {
      int   s[8];
      float n[8], v[8];
#pragma unroll
      for (int u = 0; u < 8; ++u) { s[u] = csr_src[e + u]; n[u] = csr_nrm[e + u]; }
#pragma unroll
      for (int u = 0; u < 8; ++u) v[u] = hw[(size_t)s[u] * CCH + c];
#pragma unroll
      for (int u = 0; u < 8; ++u) acc = fmaf(v[u], n[u], acc);
    }
    for (; e < e1; ++e) {
      int s = csr_src[e];
      acc = fmaf(hw[(size_t)s * CCH + c], csr_nrm[e], acc);
    }
    float v = h[(size_t)i * CCH + c] + acc;
    v = v > 0.f ? v : 0.f;
    h[(size_t)i * CCH + c] = v;
    ls += v; lq += v * v;
  }
  __shared__ float s1[256], s2[256];
  s1[threadIdx.x] = ls; s2[threadIdx.x] = lq;
  __syncthreads();
  if (threadIdx.x < 64) {
    float a = s1[threadIdx.x] + s1[threadIdx.x + 64] + s1[threadIdx.x + 128] + s1[threadIdx.x + 192];
    float b = s2[threadIdx.x] + s2[threadIdx.x + 64] + s2[threadIdx.x + 128] + s2[threadIdx.x + 192];
    atomicAdd(&stats_next[c], a);
    atomicAdd(&stats_next[64 + c], b);
  }
}

// batch is SORTED: chunked per-wave register accumulation, one atomic per
// graph-boundary per channel instead of one per node per channel.
__global__ __launch_bounds__(256) void pool_kernel(const float* __restrict__ h,
    const int* __restrict__ batch, float* __restrict__ pooled, float* __restrict__ counts) {
  int c = threadIdx.x & 63;
  int wid = (blockIdx.x * blockDim.x + threadIdx.x) >> 6;
  int nw = (gridDim.x * blockDim.x) >> 6;
  int chunk = (NN + nw - 1) / nw;
  int lo = wid * chunk;
  int hi = lo + chunk; if (hi > NN) hi = NN;
  if (lo >= hi) return;
  int g = batch[lo];
  float acc = 0.f, cnt = 0.f;
  for (int i = lo; i < hi; ++i) {
    int gi = batch[i];
    if (gi != g) {
      atomicAdd(&pooled[g * CCH + c], acc);
      if (c == 0) atomicAdd(&counts[g], cnt);
      g = gi; acc = 0.f; cnt = 0.f;
    }
    acc += h[(size_t)i * CCH + c];
    cnt += 1.f;
  }
  atomicAdd(&pooled[g * CCH + c], acc);
  if (c == 0) atomicAdd(&counts[g], cnt);
}

__global__ __launch_bounds__(128) void mlp_kernel(const float* __restrict__ pooled,
    const float* __restrict__ counts, const float* __restrict__ hid_w,
    const float* __restrict__ hid_b, const float* __restrict__ out_w,
    const float* __restrict__ out_b, float* __restrict__ out) {
  int g = blockIdx.x;
  int t = threadIdx.x;  // 128 threads
  __shared__ float p[64], hid[128];
  if (t < 64) {
    float cnt = counts[g];
    cnt = cnt > 1.f ? cnt : 1.f;
    p[t] = pooled[g * CCH + t] / cnt;
  }
  __syncthreads();
  float acc = hid_b[t];
  for (int k = 0; k < 64; ++k) acc = fmaf(p[k], hid_w[k * HID + t], acc);
  acc = acc > 0.f ? acc : 0.f;
  hid[t] = acc;
  __syncthreads();
  if (t < 64) {
    float o = out_b[t];
    for (int j = 0; j < 128; ++j) o = fmaf(hid[j], out_w[j * CCH + t], o);
    out[g * CCH + t] = o;
  }
}

extern "C" void kernel_launch(void* const* d_in, const int* in_sizes, int n_in,
                              void* d_out, int out_size, void* d_ws, size_t ws_size,
                              hipStream_t stream) {
  const int* x       = (const int*)d_in[0];
  const int* ei      = (const int*)d_in[1];
  const int* batch   = (const int*)d_in[2];
  const float* emb   = (const float*)d_in[3];
  const float* gamma = (const float*)d_in[4];
  const float* beta  = (const float*)d_in[5];
  const float* convw = (const float*)d_in[6];
  const float* convb = (const float*)d_in[7];
  const float* hid_w = (const float*)d_in[8];
  const float* hid_b = (const float*)d_in[9];
  const float* out_w = (const float*)d_in[10];
  const float* out_b = (const float*)d_in[11];
  float* out = (float*)d_out;

  float* ws     = (float*)d_ws;
  float* stats  = ws + OFF_STATS;
  float* pooled = ws + OFF_POOLED;
  float* counts = ws + OFF_COUNTS;
  float* deg    = ws + OFF_DEG;
  float* dis    = ws + OFF_DIS;
  int*   offs   = (int*)(ws + OFF_OFFS);
  int*   cursor = (int*)(ws + OFF_CURSOR);
  int*   csrsrc = (int*)(ws + OFF_CSRSRC);
  float* csrnrm = ws + OFF_CSRNRM;
  float* h      = ws + OFF_H;
  float* hw     = ws + OFF_HW;
  float* wp     = ws + OFF_WP;
  float* bias2  = ws + OFF_BIAS2;

  hipMemsetAsync(ws, 0, MEMSET_F * sizeof(float), stream);
  init_deg_kernel<<<(NN + 255) / 256, 256, 0, stream>>>(deg);
  count_deg_kernel<<<(NE + 255) / 256, 256, 0, stream>>>(ei, deg);
  dis_kernel<<<(NN + 255) / 256, 256, 0, stream>>>(deg, dis);
  scan_kernel<<<1, 1024, 0, stream>>>(deg, offs, cursor);
  csr_fill_kernel<<<(NE + 255) / 256, 256, 0, stream>>>(ei, dis, cursor, csrsrc, csrnrm);
  embed_stats_kernel<<<512, 256, 0, stream>>>(x, emb, h, stats);

  for (int l = 0; l < NLAYER; ++l) {
    bn_make_kernel<<<1, 256, 0, stream>>>(stats + l * 128, gamma + l * 64, beta + l * 64,
                                          convw + l * 4096, wp, bias2);
    gemm_kernel<<<(NN + 127) / 128, 256, 0, stream>>>(h, wp, bias2, hw);
    aggregate_kernel<<<1024, 256, 0, stream>>>(h, hw, dis, offs, csrsrc, csrnrm,
                                               convb + l * 64, stats + (l + 1) * 128);
  }

  pool_kernel<<<128, 256, 0, stream>>>(h, batch, pooled, counts);
  mlp_kernel<<<NG, 128, 0, stream>>>(pooled, counts, hid_w, hid_b, out_w, out_b, out);
}

// Round 3
// 1224.049 us; speedup vs baseline: 1.2306x; 1.0276x over previous
//
#include <hip/hip_runtime.h>

#define NN 50000
#define NE 1200000
#define CCH 64
#define NLAYER 8
#define HID 128
#define NG 128
#define BN_EPS 1e-5f
#define SCAN_NB ((NN + 255) / 256)   // 196

// ---- workspace layout (offsets in floats) ----
// [stats(9*128) | pooled(128*64) | counts(128)]  <- zeroed by one memsetAsync
enum : size_t {
  OFF_STATS  = 0,
  OFF_POOLED = 1152,
  OFF_COUNTS = 9344,
  MEMSET_F   = 9472,
  OFF_DEG    = 9472,
  OFF_DIS    = 59472,
  OFF_OFFS   = 109472,     // N+1 (+pad)
  OFF_CURSOR = 159476,
  OFF_PART   = 209476,     // 256 block partials
  OFF_CSRSRC = 209732,
  OFF_H      = 1409732,
  OFF_HW     = 4609732,
  OFF_WP     = 7809732,
  OFF_BIAS2  = 7813828,
  WS_FLOATS  = 7813892
};

__global__ void init_deg_kernel(float* __restrict__ deg) {
  int i = blockIdx.x * blockDim.x + threadIdx.x;
  if (i < NN) deg[i] = 1.0f;  // self-loop
}

__global__ void count_deg_kernel(const int* __restrict__ ei, float* __restrict__ deg) {
  int e = blockIdx.x * blockDim.x + threadIdx.x;
  if (e < NE) atomicAdd(&deg[ei[NE + e]], 1.0f);
}

// Per-block exclusive scan of (deg-1); also computes dis = rsqrt(deg).
__global__ __launch_bounds__(256) void scan_blocks_kernel(const float* __restrict__ deg,
    int* __restrict__ offs, int* __restrict__ partials, float* __restrict__ dis) {
  int i = blockIdx.x * 256 + threadIdx.x;
  int v = 0;
  if (i < NN) {
    float d = deg[i];
    v = (int)d - 1;
    dis[i] = rsqrtf(d);
  }
  __shared__ int sm[256];
  sm[threadIdx.x] = v;
  __syncthreads();
  for (int d = 1; d < 256; d <<= 1) {
    int add = (threadIdx.x >= d) ? sm[threadIdx.x - d] : 0;
    __syncthreads();
    sm[threadIdx.x] += add;
    __syncthreads();
  }
  if (i < NN) offs[i] = sm[threadIdx.x] - v;  // exclusive within block
  if (threadIdx.x == 255) partials[blockIdx.x] = sm[255];
}

__global__ __launch_bounds__(256) void scan_carry_kernel(int* __restrict__ partials) {
  int t = threadIdx.x;
  int v = (t < SCAN_NB) ? partials[t] : 0;
  __shared__ int sm[256];
  sm[t] = v;
  __syncthreads();
  for (int d = 1; d < 256; d <<= 1) {
    int add = (t >= d) ? sm[t - d] : 0;
    __syncthreads();
    sm[t] += add;
    __syncthreads();
  }
  if (t < SCAN_NB) partials[t] = sm[t] - v;  // exclusive carry per block
}

__global__ __launch_bounds__(256) void scan_apply_kernel(const int* __restrict__ partials,
    int* __restrict__ offs, int* __restrict__ cursor) {
  int i = blockIdx.x * 256 + threadIdx.x;
  if (i < NN) {
    int o = offs[i] + partials[blockIdx.x];
    offs[i] = o;
    cursor[i] = o;
  }
  if (i == 0) offs[NN] = NE;
}

__global__ void csr_fill_kernel(const int* __restrict__ ei,
    int* __restrict__ cursor, int* __restrict__ csr_src) {
  int e = blockIdx.x * blockDim.x + threadIdx.x;
  if (e < NE) {
    int r = ei[e], c = ei[NE + e];
    int p = atomicAdd(&cursor[c], 1);
    csr_src[p] = r;
  }
}

// h = emb[x]; also accumulate BN stats for layer 0
__global__ __launch_bounds__(256) void embed_stats_kernel(const int* __restrict__ x,
    const float* __restrict__ emb, float* __restrict__ h, float* __restrict__ stats0) {
  int c = threadIdx.x & 63;
  int wave = (blockIdx.x * blockDim.x + threadIdx.x) >> 6;
  int nw = (gridDim.x * blockDim.x) >> 6;
  float ls = 0.f, lq = 0.f;
  for (int i = wave; i < NN; i += nw) {
    float v = emb[x[i] * CCH + c];
    h[(size_t)i * CCH + c] = v;
    ls += v; lq += v * v;
  }
  __shared__ float s1[256], s2[256];
  s1[threadIdx.x] = ls; s2[threadIdx.x] = lq;
  __syncthreads();
  if (threadIdx.x < 64) {
    float a = s1[threadIdx.x] + s1[threadIdx.x + 64] + s1[threadIdx.x + 128] + s1[threadIdx.x + 192];
    float b = s2[threadIdx.x] + s2[threadIdx.x + 64] + s2[threadIdx.x + 128] + s2[threadIdx.x + 192];
    atomicAdd(&stats0[c], a);
    atomicAdd(&stats0[64 + c], b);
  }
}

// Fold BN into GEMM: Wp[k][j] = a[k]*W[k][j], bias2[j] = sum_k b2[k]*W[k][j]
__global__ __launch_bounds__(256) void bn_make_kernel(const float* __restrict__ stats,
    const float* __restrict__ gamma, const float* __restrict__ beta,
    const float* __restrict__ W, float* __restrict__ Wp, float* __restrict__ bias2) {
  __shared__ float a[64], b2[64];
  int t = threadIdx.x;
  if (t < 64) {
    float inv_n = 1.0f / (float)NN;
    float m = stats[t] * inv_n;
    float var = stats[64 + t] * inv_n - m * m;
    float rstd = rsqrtf(var + BN_EPS);
    float av = gamma[t] * rstd;
    a[t] = av;
    b2[t] = beta[t] - m * av;
  }
  __syncthreads();
  for (int idx = t; idx < 4096; idx += 256) {
    int k = idx >> 6;
    Wp[idx] = a[k] * W[idx];
  }
  if (t < 64) {
    float s = 0.f;
    for (int k = 0; k < 64; ++k) s += b2[k] * W[k * 64 + t];
    bias2[t] = s;
  }
}

// hw' = (h @ Wp + bias2) * dis[node]  (row-scaled so aggregation needs no per-edge norm)
__global__ __launch_bounds__(256) void gemm_kernel(const float* __restrict__ h,
    const float* __restrict__ Wp, const float* __restrict__ bias2,
    const float* __restrict__ dis, float* __restrict__ hw) {
  __shared__ float Ws[64 * 64];
  __shared__ float HsT[64 * 132];  // [k][node], stride 132: conflict-free b128 reads
  int tid = threadIdx.x;
  int nodeBase = blockIdx.x * 128;
  for (int idx = tid; idx < 4096; idx += 256) Ws[idx] = Wp[idx];
  for (int idx = tid; idx < 8192; idx += 256) {
    int node = idx >> 6, c = idx & 63;
    int gn = nodeBase + node;
    float v = (gn < NN) ? h[(size_t)gn * CCH + c] : 0.f;
    HsT[c * 132 + node] = v;
  }
  __syncthreads();
  int tc = tid & 15;   // channels tc*4..+3
  int tr = tid >> 4;   // nodes tr*8..+7
  float4 bb = *(const float4*)&bias2[tc * 4];
  float acc[8][4];
#pragma unroll
  for (int i = 0; i < 8; ++i) { acc[i][0] = bb.x; acc[i][1] = bb.y; acc[i][2] = bb.z; acc[i][3] = bb.w; }
#pragma unroll 2
  for (int k = 0; k < 64; ++k) {
    float4 wv = *(const float4*)&Ws[k * 64 + tc * 4];
    float4 h0 = *(const float4*)&HsT[k * 132 + tr * 8];
    float4 h1 = *(const float4*)&HsT[k * 132 + tr * 8 + 4];
    float hv[8] = {h0.x, h0.y, h0.z, h0.w, h1.x, h1.y, h1.z, h1.w};
    float wl[4] = {wv.x, wv.y, wv.z, wv.w};
#pragma unroll
    for (int i = 0; i < 8; ++i)
#pragma unroll
      for (int j = 0; j < 4; ++j) acc[i][j] = fmaf(hv[i], wl[j], acc[i][j]);
  }
#pragma unroll
  for (int i = 0; i < 8; ++i) {
    int gn = nodeBase + tr * 8 + i;
    if (gn < NN) {
      float dv = dis[gn];
      float4 o; o.x = acc[i][0] * dv; o.y = acc[i][1] * dv; o.z = acc[i][2] * dv; o.w = acc[i][3] * dv;
      *(float4*)&hw[(size_t)gn * CCH + tc * 4] = o;
    }
  }
}

// h = relu(h + conv_b + dis_i*(hw'_i + sum_in hw'_src)); fused BN stats for next layer.
__global__ __launch_bounds__(256) void aggregate_kernel(float* __restrict__ h,
    const float* __restrict__ hw, const float* __restrict__ dis,
    const int* __restrict__ offs, const int* __restrict__ csr_src,
    const float* __restrict__ conv_b_l, float* __restrict__ stats_next) {
  int c = threadIdx.x & 63;
  int wid = (blockIdx.x * blockDim.x + threadIdx.x) >> 6;
  int nw = (gridDim.x * blockDim.x) >> 6;
  int chunk = (NN + nw - 1) / nw;
  int lo = wid * chunk;
  int hi = lo + chunk; if (hi > NN) hi = NN;
  float cb = conv_b_l[c];
  float ls = 0.f, lq = 0.f;
  for (int i = lo; i < hi; ++i) {
    float acc = hw[(size_t)i * CCH + c];  // self term (pre-scaled by dis_i)
    int e0 = offs[i], e1 = offs[i + 1];
    int e = e0;
    for (; e + 8 <= e1; e += 8) {
      int s[8];
      float v[8];
#pragma unroll
      for (int u = 0; u < 8; ++u) s[u] = csr_src[e + u];
#pragma unroll
      for (int u = 0; u < 8; ++u) v[u] = hw[(size_t)s[u] * CCH + c];
#pragma unroll
      for (int u = 0; u < 8; ++u) acc += v[u];
    }
    for (; e < e1; ++e) acc += hw[(size_t)csr_src[e] * CCH + c];
    float v = h[(size_t)i * CCH + c] + cb + dis[i] * acc;
    v = v > 0.f ? v : 0.f;
    h[(size_t)i * CCH + c] = v;
    ls += v; lq += v * v;
  }
  __shared__ float s1[256], s2[256];
  s1[threadIdx.x] = ls; s2[threadIdx.x] = lq;
  __syncthreads();
  if (threadIdx.x < 64) {
    float a = s1[threadIdx.x] + s1[threadIdx.x + 64] + s1[threadIdx.x + 128] + s1[threadIdx.x + 192];
    float b = s2[threadIdx.x] + s2[threadIdx.x + 64] + s2[threadIdx.x + 128] + s2[threadIdx.x + 192];
    atomicAdd(&stats_next[c], a);
    atomicAdd(&stats_next[64 + c], b);
  }
}

// batch is SORTED: chunked per-wave register accumulation, one atomic per
// graph-boundary per channel.
__global__ __launch_bounds__(256) void pool_kernel(const float* __restrict__ h,
    const int* __restrict__ batch, float* __restrict__ pooled, float* __restrict__ counts) {
  int c = threadIdx.x & 63;
  int wid = (blockIdx.x * blockDim.x + threadIdx.x) >> 6;
  int nw = (gridDim.x * blockDim.x) >> 6;
  int chunk = (NN + nw - 1) / nw;
  int lo = wid * chunk;
  int hi = lo + chunk; if (hi > NN) hi = NN;
  if (lo >= hi) return;
  int g = batch[lo];
  float acc = 0.f, cnt = 0.f;
  for (int i = lo; i < hi; ++i) {
    int gi = batch[i];
    if (gi != g) {
      atomicAdd(&pooled[g * CCH + c], acc);
      if (c == 0) atomicAdd(&counts[g], cnt);
      g = gi; acc = 0.f; cnt = 0.f;
    }
    acc += h[(size_t)i * CCH + c];
    cnt += 1.f;
  }
  atomicAdd(&pooled[g * CCH + c], acc);
  if (c == 0) atomicAdd(&counts[g], cnt);
}

__global__ __launch_bounds__(128) void mlp_kernel(const float* __restrict__ pooled,
    const float* __restrict__ counts, const float* __restrict__ hid_w,
    const float* __restrict__ hid_b, const float* __restrict__ out_w,
    const float* __restrict__ out_b, float* __restrict__ out) {
  int g = blockIdx.x;
  int t = threadIdx.x;  // 128 threads
  __shared__ float p[64], hid[128];
  if (t < 64) {
    float cnt = counts[g];
    cnt = cnt > 1.f ? cnt : 1.f;
    p[t] = pooled[g * CCH + t] / cnt;
  }
  __syncthreads();
  float acc = hid_b[t];
  for (int k = 0; k < 64; ++k) acc = fmaf(p[k], hid_w[k * HID + t], acc);
  acc = acc > 0.f ? acc : 0.f;
  hid[t] = acc;
  __syncthreads();
  if (t < 64) {
    float o = out_b[t];
    for (int j = 0; j < 128; ++j) o = fmaf(hid[j], out_w[j * CCH + t], o);
    out[g * CCH + t] = o;
  }
}

extern "C" void kernel_launch(void* const* d_in, const int* in_sizes, int n_in,
                              void* d_out, int out_size, void* d_ws, size_t ws_size,
                              hipStream_t stream) {
  const int* x       = (const int*)d_in[0];
  const int* ei      = (const int*)d_in[1];
  const int* batch   = (const int*)d_in[2];
  const float* emb   = (const float*)d_in[3];
  const float* gamma = (const float*)d_in[4];
  const float* beta  = (const float*)d_in[5];
  const float* convw = (const float*)d_in[6];
  const float* convb = (const float*)d_in[7];
  const float* hid_w = (const float*)d_in[8];
  const float* hid_b = (const float*)d_in[9];
  const float* out_w = (const float*)d_in[10];
  const float* out_b = (const float*)d_in[11];
  float* out = (float*)d_out;

  float* ws     = (float*)d_ws;
  float* stats  = ws + OFF_STATS;
  float* pooled = ws + OFF_POOLED;
  float* counts = ws + OFF_COUNTS;
  float* deg    = ws + OFF_DEG;
  float* dis    = ws + OFF_DIS;
  int*   offs   = (int*)(ws + OFF_OFFS);
  int*   cursor = (int*)(ws + OFF_CURSOR);
  int*   part   = (int*)(ws + OFF_PART);
  int*   csrsrc = (int*)(ws + OFF_CSRSRC);
  float* h      = ws + OFF_H;
  float* hw     = ws + OFF_HW;
  float* wp     = ws + OFF_WP;
  float* bias2  = ws + OFF_BIAS2;

  hipMemsetAsync(ws, 0, MEMSET_F * sizeof(float), stream);
  init_deg_kernel<<<(NN + 255) / 256, 256, 0, stream>>>(deg);
  count_deg_kernel<<<(NE + 255) / 256, 256, 0, stream>>>(ei, deg);
  scan_blocks_kernel<<<SCAN_NB, 256, 0, stream>>>(deg, offs, part, dis);
  scan_carry_kernel<<<1, 256, 0, stream>>>(part);
  scan_apply_kernel<<<SCAN_NB, 256, 0, stream>>>(part, offs, cursor);
  csr_fill_kernel<<<(NE + 255) / 256, 256, 0, stream>>>(ei, cursor, csrsrc);
  embed_stats_kernel<<<512, 256, 0, stream>>>(x, emb, h, stats);

  for (int l = 0; l < NLAYER; ++l) {
    bn_make_kernel<<<1, 256, 0, stream>>>(stats + l * 128, gamma + l * 64, beta + l * 64,
                                          convw + l * 4096, wp, bias2);
    gemm_kernel<<<(NN + 127) / 128, 256, 0, stream>>>(h, wp, bias2, dis, hw);
    aggregate_kernel<<<2048, 256, 0, stream>>>(h, hw, dis, offs, csrsrc,
                                               convb + l * 64, stats + (l + 1) * 128);
  }

  pool_kernel<<<128, 256, 0, stream>>>(h, batch, pooled, counts);
  mlp_kernel<<<NG, 128, 0, stream>>>(pooled, counts, hid_w, hid_b, out_w, out_b, out);
}

// Round 4
// 1102.088 us; speedup vs baseline: 1.3667x; 1.1107x over previous
//
#include <hip/hip_runtime.h>

#define NN 50000
#define NE 1200000
#define CCH 64
#define NLAYER 8
#define HID 128
#define NG 128
#define BN_EPS 1e-5f
#define SCAN_NB ((NN + 255) / 256)   // 196

// ---- workspace layout (offsets in floats) ----
// [stats(9*128) | pooled(128*64) | counts(128)]  <- zeroed by one memsetAsync
enum : size_t {
  OFF_STATS  = 0,
  OFF_POOLED = 1152,
  OFF_COUNTS = 9344,
  MEMSET_F   = 9472,
  OFF_DEG    = 9472,
  OFF_DIS    = 59472,
  OFF_OFFS   = 109472,     // N+1 (+pad)
  OFF_CURSOR = 159476,
  OFF_PART   = 209476,     // 256 block partials
  OFF_CSRSRC = 209732,
  OFF_H      = 1409732,
  OFF_HW     = 4609732,    // now ushort[N*64] (bf16), reinterpreted
  OFF_WP     = 7809732,
  OFF_BIAS2  = 7813828,
  WS_FLOATS  = 7813892
};

__device__ __forceinline__ float bf2f(unsigned int hs) {
  union { unsigned int u; float f; } c; c.u = hs << 16; return c.f;
}
__device__ __forceinline__ unsigned int f2bf(float x) {
  union { float f; unsigned int u; } c; c.f = x;
  return (c.u + 0x7fffu + ((c.u >> 16) & 1u)) >> 16;  // RNE
}

__global__ void init_deg_kernel(float* __restrict__ deg) {
  int i = blockIdx.x * blockDim.x + threadIdx.x;
  if (i < NN) deg[i] = 1.0f;  // self-loop
}

__global__ void count_deg_kernel(const int* __restrict__ ei, float* __restrict__ deg) {
  int e = blockIdx.x * blockDim.x + threadIdx.x;
  if (e < NE) atomicAdd(&deg[ei[NE + e]], 1.0f);
}

// Per-block exclusive scan of (deg-1); also computes dis = rsqrt(deg).
__global__ __launch_bounds__(256) void scan_blocks_kernel(const float* __restrict__ deg,
    int* __restrict__ offs, int* __restrict__ partials, float* __restrict__ dis) {
  int i = blockIdx.x * 256 + threadIdx.x;
  int v = 0;
  if (i < NN) {
    float d = deg[i];
    v = (int)d - 1;
    dis[i] = rsqrtf(d);
  }
  __shared__ int sm[256];
  sm[threadIdx.x] = v;
  __syncthreads();
  for (int d = 1; d < 256; d <<= 1) {
    int add = (threadIdx.x >= d) ? sm[threadIdx.x - d] : 0;
    __syncthreads();
    sm[threadIdx.x] += add;
    __syncthreads();
  }
  if (i < NN) offs[i] = sm[threadIdx.x] - v;  // exclusive within block
  if (threadIdx.x == 255) partials[blockIdx.x] = sm[255];
}

__global__ __launch_bounds__(256) void scan_carry_kernel(int* __restrict__ partials) {
  int t = threadIdx.x;
  int v = (t < SCAN_NB) ? partials[t] : 0;
  __shared__ int sm[256];
  sm[t] = v;
  __syncthreads();
  for (int d = 1; d < 256; d <<= 1) {
    int add = (t >= d) ? sm[t - d] : 0;
    __syncthreads();
    sm[t] += add;
    __syncthreads();
  }
  if (t < SCAN_NB) partials[t] = sm[t] - v;  // exclusive carry per block
}

__global__ __launch_bounds__(256) void scan_apply_kernel(const int* __restrict__ partials,
    int* __restrict__ offs, int* __restrict__ cursor) {
  int i = blockIdx.x * 256 + threadIdx.x;
  if (i < NN) {
    int o = offs[i] + partials[blockIdx.x];
    offs[i] = o;
    cursor[i] = o;
  }
  if (i == 0) offs[NN] = NE;
}

__global__ void csr_fill_kernel(const int* __restrict__ ei,
    int* __restrict__ cursor, int* __restrict__ csr_src) {
  int e = blockIdx.x * blockDim.x + threadIdx.x;
  if (e < NE) {
    int r = ei[e], c = ei[NE + e];
    int p = atomicAdd(&cursor[c], 1);
    csr_src[p] = r;
  }
}

// h = emb[x]; also accumulate BN stats for layer 0
__global__ __launch_bounds__(256) void embed_stats_kernel(const int* __restrict__ x,
    const float* __restrict__ emb, float* __restrict__ h, float* __restrict__ stats0) {
  int c = threadIdx.x & 63;
  int wave = (blockIdx.x * blockDim.x + threadIdx.x) >> 6;
  int nw = (gridDim.x * blockDim.x) >> 6;
  float ls = 0.f, lq = 0.f;
  for (int i = wave; i < NN; i += nw) {
    float v = emb[x[i] * CCH + c];
    h[(size_t)i * CCH + c] = v;
    ls += v; lq += v * v;
  }
  __shared__ float s1[256], s2[256];
  s1[threadIdx.x] = ls; s2[threadIdx.x] = lq;
  __syncthreads();
  if (threadIdx.x < 64) {
    float a = s1[threadIdx.x] + s1[threadIdx.x + 64] + s1[threadIdx.x + 128] + s1[threadIdx.x + 192];
    float b = s2[threadIdx.x] + s2[threadIdx.x + 64] + s2[threadIdx.x + 128] + s2[threadIdx.x + 192];
    atomicAdd(&stats0[c], a);
    atomicAdd(&stats0[64 + c], b);
  }
}

// Fold BN into GEMM: Wp[k][j] = a[k]*W[k][j], bias2[j] = sum_k b2[k]*W[k][j]
__global__ __launch_bounds__(256) void bn_make_kernel(const float* __restrict__ stats,
    const float* __restrict__ gamma, const float* __restrict__ beta,
    const float* __restrict__ W, float* __restrict__ Wp, float* __restrict__ bias2) {
  __shared__ float a[64], b2[64];
  int t = threadIdx.x;
  if (t < 64) {
    float inv_n = 1.0f / (float)NN;
    float m = stats[t] * inv_n;
    float var = stats[64 + t] * inv_n - m * m;
    float rstd = rsqrtf(var + BN_EPS);
    float av = gamma[t] * rstd;
    a[t] = av;
    b2[t] = beta[t] - m * av;
  }
  __syncthreads();
  for (int idx = t; idx < 4096; idx += 256) {
    int k = idx >> 6;
    Wp[idx] = a[k] * W[idx];
  }
  if (t < 64) {
    float s = 0.f;
    for (int k = 0; k < 64; ++k) s += b2[k] * W[k * 64 + t];
    bias2[t] = s;
  }
}

// hw' = bf16((h @ Wp + bias2) * dis[node])  (row-scaled; bf16 halves gather bytes)
__global__ __launch_bounds__(256) void gemm_kernel(const float* __restrict__ h,
    const float* __restrict__ Wp, const float* __restrict__ bias2,
    const float* __restrict__ dis, unsigned short* __restrict__ hwb) {
  __shared__ float Ws[64 * 64];
  __shared__ float HsT[64 * 132];  // [k][node], stride 132: conflict-free b128 reads
  int tid = threadIdx.x;
  int nodeBase = blockIdx.x * 128;
  for (int idx = tid; idx < 4096; idx += 256) Ws[idx] = Wp[idx];
  for (int idx = tid; idx < 8192; idx += 256) {
    int node = idx >> 6, c = idx & 63;
    int gn = nodeBase + node;
    float v = (gn < NN) ? h[(size_t)gn * CCH + c] : 0.f;
    HsT[c * 132 + node] = v;
  }
  __syncthreads();
  int tc = tid & 15;   // channels tc*4..+3
  int tr = tid >> 4;   // nodes tr*8..+7
  float4 bb = *(const float4*)&bias2[tc * 4];
  float acc[8][4];
#pragma unroll
  for (int i = 0; i < 8; ++i) { acc[i][0] = bb.x; acc[i][1] = bb.y; acc[i][2] = bb.z; acc[i][3] = bb.w; }
#pragma unroll 2
  for (int k = 0; k < 64; ++k) {
    float4 wv = *(const float4*)&Ws[k * 64 + tc * 4];
    float4 h0 = *(const float4*)&HsT[k * 132 + tr * 8];
    float4 h1 = *(const float4*)&HsT[k * 132 + tr * 8 + 4];
    float hv[8] = {h0.x, h0.y, h0.z, h0.w, h1.x, h1.y, h1.z, h1.w};
    float wl[4] = {wv.x, wv.y, wv.z, wv.w};
#pragma unroll
    for (int i = 0; i < 8; ++i)
#pragma unroll
      for (int j = 0; j < 4; ++j) acc[i][j] = fmaf(hv[i], wl[j], acc[i][j]);
  }
#pragma unroll
  for (int i = 0; i < 8; ++i) {
    int gn = nodeBase + tr * 8 + i;
    if (gn < NN) {
      float dv = dis[gn];
      uint2 o;
      o.x = f2bf(acc[i][0] * dv) | (f2bf(acc[i][1] * dv) << 16);
      o.y = f2bf(acc[i][2] * dv) | (f2bf(acc[i][3] * dv) << 16);
      *(uint2*)&hwb[(size_t)gn * CCH + tc * 4] = o;
    }
  }
}

// h = relu(h + conv_b + dis_i*(hw'_i + sum_in hw'_src)); fused BN stats.
// Half-wave per edge: lane = channel-pair (ushort2 = 4B), 2 edges per wave
// in flight per unroll slot -> 16 independent gathers outstanding.
__global__ __launch_bounds__(256) void aggregate_kernel(float* __restrict__ h,
    const unsigned short* __restrict__ hwb, const float* __restrict__ dis,
    const int* __restrict__ offs, const int* __restrict__ csr_src,
    const float* __restrict__ conv_b_l, float* __restrict__ stats_next) {
  int tid = threadIdx.x;
  int lane = tid & 63;
  int half = lane >> 5;     // which edge of the pair
  int l = lane & 31;        // channel pair: channels 2l, 2l+1
  int wid = (blockIdx.x * blockDim.x + tid) >> 6;
  int nw = (gridDim.x * blockDim.x) >> 6;
  int chunk = (NN + nw - 1) / nw;
  int lo = wid * chunk;
  int hi = lo + chunk; if (hi > NN) hi = NN;
  float2 cb = ((const float2*)conv_b_l)[l];
  float ls0 = 0.f, ls1 = 0.f, lq0 = 0.f, lq1 = 0.f;
  for (int i = lo; i < hi; ++i) {
    float a0, a1;
    if (half == 0) {  // self term (pre-scaled by dis_i)
      unsigned int sv = *(const unsigned int*)&hwb[(size_t)i * CCH + 2 * l];
      a0 = bf2f(sv & 0xffffu); a1 = bf2f(sv >> 16);
    } else { a0 = 0.f; a1 = 0.f; }
    int e0 = offs[i], e1 = offs[i + 1];
    int ee = e0 + half;
    for (; ee + 15 <= e1; ee += 16) {  // 8 edges for this half
      int s[8]; unsigned int v[8];
#pragma unroll
      for (int u = 0; u < 8; ++u) s[u] = csr_src[ee + 2 * u];
#pragma unroll
      for (int u = 0; u < 8; ++u) v[u] = *(const unsigned int*)&hwb[(size_t)s[u] * CCH + 2 * l];
#pragma unroll
      for (int u = 0; u < 8; ++u) { a0 += bf2f(v[u] & 0xffffu); a1 += bf2f(v[u] >> 16); }
    }
    for (; ee < e1; ee += 2) {
      unsigned int v = *(const unsigned int*)&hwb[(size_t)csr_src[ee] * CCH + 2 * l];
      a0 += bf2f(v & 0xffffu); a1 += bf2f(v >> 16);
    }
    a0 += __shfl_xor(a0, 32);
    a1 += __shfl_xor(a1, 32);
    if (half == 0) {
      float2 hv = ((const float2*)h)[(size_t)i * 32 + l];
      float d = dis[i];
      float v0 = hv.x + cb.x + d * a0;
      float v1 = hv.y + cb.y + d * a1;
      v0 = v0 > 0.f ? v0 : 0.f;
      v1 = v1 > 0.f ? v1 : 0.f;
      float2 o; o.x = v0; o.y = v1;
      ((float2*)h)[(size_t)i * 32 + l] = o;
      ls0 += v0; lq0 += v0 * v0; ls1 += v1; lq1 += v1 * v1;
    }
  }
  __shared__ float2 s1[256], s2[256];
  float2 t1; t1.x = ls0; t1.y = ls1;
  float2 t2; t2.x = lq0; t2.y = lq1;
  s1[tid] = t1; s2[tid] = t2;
  __syncthreads();
  if (tid < 64) {  // tid = channel c; lane c>>1 component c&1 of each wave
    int pair = tid >> 1, comp = tid & 1;
    float a = 0.f, b = 0.f;
#pragma unroll
    for (int w = 0; w < 4; ++w) {
      float2 u1 = s1[w * 64 + pair];
      float2 u2 = s2[w * 64 + pair];
      a += comp ? u1.y : u1.x;
      b += comp ? u2.y : u2.x;
    }
    atomicAdd(&stats_next[tid], a);
    atomicAdd(&stats_next[64 + tid], b);
  }
}

// batch is SORTED: chunked per-wave register accumulation, one atomic per
// graph-boundary per channel.
__global__ __launch_bounds__(256) void pool_kernel(const float* __restrict__ h,
    const int* __restrict__ batch, float* __restrict__ pooled, float* __restrict__ counts) {
  int c = threadIdx.x & 63;
  int wid = (blockIdx.x * blockDim.x + threadIdx.x) >> 6;
  int nw = (gridDim.x * blockDim.x) >> 6;
  int chunk = (NN + nw - 1) / nw;
  int lo = wid * chunk;
  int hi = lo + chunk; if (hi > NN) hi = NN;
  if (lo >= hi) return;
  int g = batch[lo];
  float acc = 0.f, cnt = 0.f;
  for (int i = lo; i < hi; ++i) {
    int gi = batch[i];
    if (gi != g) {
      atomicAdd(&pooled[g * CCH + c], acc);
      if (c == 0) atomicAdd(&counts[g], cnt);
      g = gi; acc = 0.f; cnt = 0.f;
    }
    acc += h[(size_t)i * CCH + c];
    cnt += 1.f;
  }
  atomicAdd(&pooled[g * CCH + c], acc);
  if (c == 0) atomicAdd(&counts[g], cnt);
}

__global__ __launch_bounds__(128) void mlp_kernel(const float* __restrict__ pooled,
    const float* __restrict__ counts, const float* __restrict__ hid_w,
    const float* __restrict__ hid_b, const float* __restrict__ out_w,
    const float* __restrict__ out_b, float* __restrict__ out) {
  int g = blockIdx.x;
  int t = threadIdx.x;  // 128 threads
  __shared__ float p[64], hid[128];
  if (t < 64) {
    float cnt = counts[g];
    cnt = cnt > 1.f ? cnt : 1.f;
    p[t] = pooled[g * CCH + t] / cnt;
  }
  __syncthreads();
  float acc = hid_b[t];
  for (int k = 0; k < 64; ++k) acc = fmaf(p[k], hid_w[k * HID + t], acc);
  acc = acc > 0.f ? acc : 0.f;
  hid[t] = acc;
  __syncthreads();
  if (t < 64) {
    float o = out_b[t];
    for (int j = 0; j < 128; ++j) o = fmaf(hid[j], out_w[j * CCH + t], o);
    out[g * CCH + t] = o;
  }
}

extern "C" void kernel_launch(void* const* d_in, const int* in_sizes, int n_in,
                              void* d_out, int out_size, void* d_ws, size_t ws_size,
                              hipStream_t stream) {
  const int* x       = (const int*)d_in[0];
  const int* ei      = (const int*)d_in[1];
  const int* batch   = (const int*)d_in[2];
  const float* emb   = (const float*)d_in[3];
  const float* gamma = (const float*)d_in[4];
  const float* beta  = (const float*)d_in[5];
  const float* convw = (const float*)d_in[6];
  const float* convb = (const float*)d_in[7];
  const float* hid_w = (const float*)d_in[8];
  const float* hid_b = (const float*)d_in[9];
  const float* out_w = (const float*)d_in[10];
  const float* out_b = (const float*)d_in[11];
  float* out = (float*)d_out;

  float* ws     = (float*)d_ws;
  float* stats  = ws + OFF_STATS;
  float* pooled = ws + OFF_POOLED;
  float* counts = ws + OFF_COUNTS;
  float* deg    = ws + OFF_DEG;
  float* dis    = ws + OFF_DIS;
  int*   offs   = (int*)(ws + OFF_OFFS);
  int*   cursor = (int*)(ws + OFF_CURSOR);
  int*   part   = (int*)(ws + OFF_PART);
  int*   csrsrc = (int*)(ws + OFF_CSRSRC);
  float* h      = ws + OFF_H;
  unsigned short* hwb = (unsigned short*)(ws + OFF_HW);
  float* wp     = ws + OFF_WP;
  float* bias2  = ws + OFF_BIAS2;

  hipMemsetAsync(ws, 0, MEMSET_F * sizeof(float), stream);
  init_deg_kernel<<<(NN + 255) / 256, 256, 0, stream>>>(deg);
  count_deg_kernel<<<(NE + 255) / 256, 256, 0, stream>>>(ei, deg);
  scan_blocks_kernel<<<SCAN_NB, 256, 0, stream>>>(deg, offs, part, dis);
  scan_carry_kernel<<<1, 256, 0, stream>>>(part);
  scan_apply_kernel<<<SCAN_NB, 256, 0, stream>>>(part, offs, cursor);
  csr_fill_kernel<<<(NE + 255) / 256, 256, 0, stream>>>(ei, cursor, csrsrc);
  embed_stats_kernel<<<512, 256, 0, stream>>>(x, emb, h, stats);

  for (int l = 0; l < NLAYER; ++l) {
    bn_make_kernel<<<1, 256, 0, stream>>>(stats + l * 128, gamma + l * 64, beta + l * 64,
                                          convw + l * 4096, wp, bias2);
    gemm_kernel<<<(NN + 127) / 128, 256, 0, stream>>>(h, wp, bias2, dis, hwb);
    aggregate_kernel<<<2048, 256, 0, stream>>>(h, hwb, dis, offs, csrsrc,
                                               convb + l * 64, stats + (l + 1) * 128);
  }

  pool_kernel<<<128, 256, 0, stream>>>(h, batch, pooled, counts);
  mlp_kernel<<<NG, 128, 0, stream>>>(pooled, counts, hid_w, hid_b, out_w, out_b, out);
}